// Round 6
// baseline (405.275 us; speedup 1.0000x reference)
//
#include <hip/hip_runtime.h>
#include <stdint.h>

// Problem constants (match reference)
#define NP 32    // num networks (P)
#define NH 128   // hidden (H)
#define NB 32    // batch (B)
#define NT 256   // time (T)
#define FH 512   // 4*H

typedef __attribute__((ext_vector_type(4))) float float4_t;
typedef __attribute__((ext_vector_type(8))) __bf16 bf16x8;
typedef __attribute__((ext_vector_type(4))) __bf16 bf16x4;

static __device__ __forceinline__ float4_t mfma_bf16(bf16x8 a, bf16x8 b, float4_t c) {
  return __builtin_amdgcn_mfma_f32_16x16x32_bf16(a, b, c, 0, 0, 0);
}

#define LOG2E 1.4426950408889634f

// Raw workgroup barrier: drains LDS ops only (cross-wave h visibility), does
// NOT drain vmcnt — pending global loads/stores stay in flight across it.
#define BAR() __asm__ volatile("s_waitcnt lgkmcnt(0)\n\ts_barrier" ::: "memory")

// ---------------------------------------------------------------------------
// R14: R13 retry, hardened. R13 aborted before any dispatch (no counters, no
// HIP error text) — prime suspect is the amdgpu_waves_per_eu(4,4) attribute
// (only never-before-exercised compiler-stressing construct); all addresses
// audited in-bounds. This round keeps the attribute but removes every other
// novelty so a repeat abort convicts it:
//   - final-iteration x load now guarded (no overfetch, was the only other
//     nonstandard memory pattern);
//   - __threadfence() before epilogue reads (correctness: BAR is lgkm-only
//     and vmcnt(0) only orders OWN stores; epilogue reads OTHER waves' h).
// Theory (R12 evidence): M=2 runs 1660 cyc/step but unified regs ~160 kept
// occupancy at 1 block/CU. Demand cut to ~125 (head-ectomy: h dumped to ws
// as bf16, VALU head in epilogue; bias4->bsc; bf16 X prepass kills f32 xv
// staging; gate-streamed chains keep 4 acc regs live, not 32) + (4,4) pin
// => 2 blocks/CU; each block's ~800cyc/step exposure is filled by the other
// block's 164-MFMA burst. Pair ~ max(2x795, 1660) ~ 1700 cyc per TWO steps.
// SESSION RULES: launch_bounds 2nd arg never !=1 (R9-R11: 64-reg spill
// death); no DS ops in loop beyond h write/read (R5); h via LDS only (R5).
// ---------------------------------------------------------------------------

// Prepass: X f32 -> bf16 into ws (same [B][T][P] layout). 262144 elems.
__global__ __launch_bounds__(512, 1) void xcvt(
    const float* __restrict__ X, __bf16* __restrict__ Xb)
{
  const int i = (blockIdx.x * 512 + threadIdx.x) * 4;
  float4_t v = *(const float4_t*)(X + i);
  bf16x4 o;
#pragma unroll
  for (int j = 0; j < 4; ++j) o[j] = (__bf16)v[j];
  *(bf16x4*)(Xb + i) = o;
}

__global__ __attribute__((amdgpu_flat_work_group_size(512, 512),
                          amdgpu_waves_per_eu(4, 4)))
void clstm_fused2(
    const __bf16* __restrict__ Xb, const float* __restrict__ Wih,
    const float* __restrict__ Whh, const float* __restrict__ bih,
    const float* __restrict__ bhh, const float* __restrict__ Wout,
    const float* __restrict__ bout, float* __restrict__ out,
    __bf16* __restrict__ wsH)
{
  const int net = blockIdx.x >> 4, bq = blockIdx.x & 15;
  const int tid = threadIdx.x;
  const int w = tid >> 6, lane = tid & 63;
  const int quad = lane >> 4, l16 = lane & 15;

  // h A-fragments, double buffered: [buf][kc][kquad][m<4][j]
  __shared__ __bf16 hfrag[2][4][4][4][8];   // 2 KB

  { ((int*)hfrag)[tid] = 0; }   // h0 = 0, both buffers
  __syncthreads();

  // ---- weights -> register B-fragments (one-time) ----
  // B-frag layout for 16x16x32: lane holds B[k = quad*8 + j][n = l16].
  bf16x8 bfrag[4][5];
  float bsc[4];   // per-gate scalar bias (this lane's col), added at gv
#pragma unroll
  for (int g = 0; g < 4; ++g) {
    const float scale = (g == 2) ? (-2.0f*LOG2E) : (-LOG2E);
    const int col = g*NH + w*16 + l16;
#pragma unroll
    for (int kc = 0; kc < 5; ++kc) {
      const float* src = (kc == 0) ? (Wih + ((size_t)net*FH + col)*NP + quad*8)
                                   : (Whh + ((size_t)net*FH + col)*NH + (kc-1)*32 + quad*8);
      bf16x8 bf;
#pragma unroll
      for (int j = 0; j < 8; ++j) bf[j] = (__bf16)(src[j] * scale);
      bfrag[g][kc] = bf;
    }
    bsc[g] = (bih[net*FH + col] + bhh[net*FH + col]) * scale;
  }

  // c state, PRE-SCALED by -2log2e
  float cs = 0.f;
  const float S2 = -2.0f*LOG2E;

  // x source (bf16, prepass layout == X layout): batch bq*2 + (l16&1)
  int xoff = (bq*2 + (l16 & 1))*(NT*NP) + quad*8;   // elem offset

  // h write coords for unit u = w*16 + l16; row = quad&1 (lane's batch)
  const int kcp = w >> 1, q2 = ((w & 1) << 1) | (l16 >> 3), jj = l16 & 7;
  const int mrow = quad & 1;

  // h-dump offset (shorts): [block][t][m][u], u = w*16+l16; quads 0,1 store
  int hoff = (blockIdx.x << 16) + quad*128 + w*16 + l16;

  // preload ax for t=0
  bf16x8 ax = *(const bf16x8*)(Xb + xoff);
  xoff += NP;

  for (int t = 0; t < NT; ++t) {
    const int rd = t & 1, wr = rd ^ 1;

    // ---- 1. h A-frags (row = l16&1; 8-lane same-address broadcast) ----
    bf16x8 ah[4];
#pragma unroll
    for (int kc = 0; kc < 4; ++kc)
      ah[kc] = *(const bf16x8*)&hfrag[rd][kc][quad][l16 & 1][0];

    // ---- 2. gate-streamed MFMA chains, extract gv per gate ----
    // a0: x -> h0 -> h1 (3-deep); a1: h2 -> h3 (2-deep); 8 indep chains
    // across 4 gates; only ~4 acc regs live at once (not 32).
    float gv[4];
#pragma unroll
    for (int g = 0; g < 4; ++g) {
      float4_t a0 = mfma_bf16(ax, bfrag[g][0], (float4_t){0.f,0.f,0.f,0.f});
      float4_t a1 = mfma_bf16(ah[2], bfrag[g][3], (float4_t){0.f,0.f,0.f,0.f});
      a0 = mfma_bf16(ah[0], bfrag[g][1], a0);
      a1 = mfma_bf16(ah[3], bfrag[g][4], a1);
      a0 = mfma_bf16(ah[1], bfrag[g][2], a0);
      float4_t s = a0 + a1;
      gv[g] = ((quad & 1) ? s[1] : s[0]) + bsc[g];   // batch = quad&1
    }

    // ---- 3. reload ax for t+1 (guarded; ax dead after gate loop); load
    // shadow = activation + h-write + BAR ----
    if (t + 1 < NT) {
      ax = *(const bf16x8*)(Xb + xoff);
    }
    xoff += NP;

    // ---- 4. activation + state update ----
    float h;
    {
      float ei = __builtin_amdgcn_exp2f(gv[0]);
      float ig = __builtin_amdgcn_rcpf(1.0f + ei);            // sigmoid(i)
      float ef = __builtin_amdgcn_exp2f(gv[1]);
      float fg = __builtin_amdgcn_rcpf(1.0f + ef);            // sigmoid(f)
      float eg = __builtin_amdgcn_exp2f(fminf(gv[2], 126.0f));
      float rg = __builtin_amdgcn_rcpf(1.0f + eg);
      float t0 = S2 * rg;
      float gg2 = t0 - t0 * eg;                               // tanh(g)*S2
      float eo = __builtin_amdgcn_exp2f(gv[3]);
      float og = __builtin_amdgcn_rcpf(1.0f + eo);            // sigmoid(o)
      cs = fg * cs + ig * gg2;                                // c * S2
      float ec = __builtin_amdgcn_exp2f(fminf(cs, 126.0f));
      float rc = __builtin_amdgcn_rcpf(1.0f + ec);
      float th = rc - ec * rc;                                // tanh(c)
      h = og * th;
    }

    // ---- 5. write h': LDS (next step's A-frags) + async global dump ----
    if (quad < 2) {
      hfrag[wr][kcp][q2][mrow][jj] = (__bf16)h;
      wsH[hoff] = (__bf16)h;     // global_store_short, flies across BAR
    }
    hoff += 256;

    BAR();  // lgkmcnt-only barrier
  }

  // ---- epilogue: 1x1-conv head in f32 VALU from the h dump ----
  // Fence: BAR never drained vmcnt, and the reads below consume OTHER
  // waves' global stores -> agent-scope fence + barrier.
  __threadfence();
  __syncthreads();
  // stage Wout[net] (128 f32) in LDS (hfrag storage reused)
  float* ldsW = (float*)&hfrag[0][0][0][0][0];
  if (tid < NH) ldsW[tid] = Wout[net*NH + tid];
  __syncthreads();

  const int tt = tid >> 1, m = tid & 1;          // 512 thr = 256 t x 2 m
  const __bf16* hp = wsH + ((size_t)blockIdx.x << 16) + tt*256 + m*128;
  float s = bout[net];
#pragma unroll
  for (int kc = 0; kc < 16; ++kc) {
    bf16x8 h8 = *(const bf16x8*)(hp + kc*8);
#pragma unroll
    for (int j = 0; j < 8; ++j)
      s += (float)h8[j] * ldsW[kc*8 + j];        // broadcast LDS read
  }
  out[(size_t)(bq*2 + m)*(NT*NP) + tt*NP + net] = s;
}

// ---------------------------------------------------------------------------
// Fallback (ws too small): R8 kernel verbatim — M=4 / 256 blocks, fused
// head, 219us rocprof. No workspace use.
// ---------------------------------------------------------------------------
__global__ __launch_bounds__(512, 1) void clstm_fused_fb(
    const float* __restrict__ X, const float* __restrict__ Wih,
    const float* __restrict__ Whh, const float* __restrict__ bih,
    const float* __restrict__ bhh, const float* __restrict__ Wout,
    const float* __restrict__ bout, float* __restrict__ out)
{
  const int net = blockIdx.x >> 3, bq = blockIdx.x & 7;
  const int tid = threadIdx.x;
  const int w = tid >> 6, lane = tid & 63;
  const int quad = lane >> 4, l16 = lane & 15;

  __shared__ __bf16 hfrag[2][4][4][4][8];
  { ((int*)hfrag)[tid] = 0; }
  __syncthreads();

  bf16x8 bfrag[4][5];
  float4_t bias4[4];
#pragma unroll
  for (int g = 0; g < 4; ++g) {
    const float scale = (g == 2) ? (-2.0f*LOG2E) : (-LOG2E);
    const int col = g*NH + w*16 + l16;
#pragma unroll
    for (int kc = 0; kc < 5; ++kc) {
      const float* src = (kc == 0) ? (Wih + ((size_t)net*FH + col)*NP + quad*8)
                                   : (Whh + ((size_t)net*FH + col)*NH + (kc-1)*32 + quad*8);
      bf16x8 bf;
#pragma unroll
      for (int j = 0; j < 8; ++j) bf[j] = (__bf16)(src[j] * scale);
      bfrag[g][kc] = bf;
    }
    const float b = (bih[net*FH + col] + bhh[net*FH + col]) * scale;
    bias4[g] = (float4_t){b, b, b, b};
  }

  bf16x8 wof[4];
#pragma unroll
  for (int kc = 0; kc < 4; ++kc) {
    const float* wp = Wout + net*NH + kc*32 + quad*8;
#pragma unroll
    for (int j = 0; j < 8; ++j) wof[kc][j] = (__bf16)wp[j];
  }
  const float bo = bout[net];

  float cs = 0.f;
  const float S2 = -2.0f*LOG2E;

  const float* xrow = X + (size_t)(bq*4 + (l16 & 3))*(NT*NP) + quad*8;
  const int kcp = w >> 1, q2 = ((w & 1) << 1) | (l16 >> 3), jj = l16 & 7;
  float* outp = out + ((size_t)bq*4)*(NT*NP) + net;

  bf16x8 ax;
  {
    float xv0[8];
    *(float4_t*)&xv0[0] = *(const float4_t*)xrow;
    *(float4_t*)&xv0[4] = *(const float4_t*)(xrow + 4);
#pragma unroll
    for (int j = 0; j < 8; ++j) ax[j] = (__bf16)xv0[j];
  }
  const float* xp = xrow + NP;
  float xv[8] = {0.f,0.f,0.f,0.f,0.f,0.f,0.f,0.f};

  for (int t = 0; t < NT; ++t) {
    const int rd = t & 1, wr = rd ^ 1;
    bf16x8 ah[4];
#pragma unroll
    for (int kc = 0; kc < 4; ++kc)
      ah[kc] = *(const bf16x8*)&hfrag[rd][kc][quad][l16 & 3][0];
    float4_t accx[4];
#pragma unroll
    for (int g = 0; g < 4; ++g)
      accx[g] = mfma_bf16(ax, bfrag[g][0], bias4[g]);
    if (t + 1 < NT) {
      *(float4_t*)&xv[0] = *(const float4_t*)xp;
      *(float4_t*)&xv[4] = *(const float4_t*)(xp + 4);
    }
    float4_t acc[4];
#pragma unroll
    for (int g = 0; g < 4; ++g) {
      float4_t a0 = mfma_bf16(ah[0], bfrag[g][1], accx[g]);
      float4_t a1 = mfma_bf16(ah[2], bfrag[g][3], (float4_t){0.f,0.f,0.f,0.f});
      a0 = mfma_bf16(ah[1], bfrag[g][2], a0);
      a1 = mfma_bf16(ah[3], bfrag[g][4], a1);
      acc[g] = a0 + a1;
    }
    float gv[4];
#pragma unroll
    for (int g = 0; g < 4; ++g) {
      float a01 = (quad & 1) ? acc[g][1] : acc[g][0];
      float a23 = (quad & 1) ? acc[g][3] : acc[g][2];
      gv[g] = (quad & 2) ? a23 : a01;
    }
    float h;
    {
      float ei = __builtin_amdgcn_exp2f(gv[0]);
      float ig = __builtin_amdgcn_rcpf(1.0f + ei);
      float ef = __builtin_amdgcn_exp2f(gv[1]);
      float fg = __builtin_amdgcn_rcpf(1.0f + ef);
      float eg = __builtin_amdgcn_exp2f(fminf(gv[2], 126.0f));
      float rg = __builtin_amdgcn_rcpf(1.0f + eg);
      float t0 = S2 * rg;
      float gg2 = t0 - t0 * eg;
      float eo = __builtin_amdgcn_exp2f(gv[3]);
      float og = __builtin_amdgcn_rcpf(1.0f + eo);
      cs = fg * cs + ig * gg2;
      float ec = __builtin_amdgcn_exp2f(fminf(cs, 126.0f));
      float rc = __builtin_amdgcn_rcpf(1.0f + ec);
      float th = rc - ec * rc;
      h = og * th;
    }
    hfrag[wr][kcp][q2][quad][jj] = (__bf16)h;
    if (w == 0 && t > 0) {
      float4_t p0 = {bo, bo, bo, bo};
      float4_t p1 = {0.f, 0.f, 0.f, 0.f};
      p0 = mfma_bf16(ah[0], wof[0], p0);
      p1 = mfma_bf16(ah[2], wof[2], p1);
      p0 = mfma_bf16(ah[1], wof[1], p0);
      p1 = mfma_bf16(ah[3], wof[3], p1);
      float4_t po = p0 + p1;
      if (lane == 0) {
#pragma unroll
        for (int r = 0; r < 4; ++r)
          outp[(size_t)r*(NT*NP) + (t - 1)*NP] = po[r];
      }
    }
#pragma unroll
    for (int j = 0; j < 8; ++j) ax[j] = (__bf16)xv[j];
    xp += NP;
    BAR();
  }

  if (w == 0) {
    bf16x8 ahf[4];
#pragma unroll
    for (int kc = 0; kc < 4; ++kc)
      ahf[kc] = *(const bf16x8*)&hfrag[NT & 1][kc][quad][l16 & 3][0];
    float4_t p0 = {bo, bo, bo, bo};
    float4_t p1 = {0.f, 0.f, 0.f, 0.f};
    p0 = mfma_bf16(ahf[0], wof[0], p0);
    p1 = mfma_bf16(ahf[2], wof[2], p1);
    p0 = mfma_bf16(ahf[1], wof[1], p0);
    p1 = mfma_bf16(ahf[3], wof[3], p1);
    float4_t po = p0 + p1;
    if (lane == 0) {
#pragma unroll
      for (int r = 0; r < 4; ++r)
        outp[(size_t)r*(NT*NP) + (NT - 1)*NP] = po[r];
    }
  }
}

extern "C" void kernel_launch(void* const* d_in, const int* in_sizes, int n_in,
                              void* d_out, int out_size, void* d_ws, size_t ws_size,
                              hipStream_t stream) {
  const float* X    = (const float*)d_in[0];
  const float* Wih  = (const float*)d_in[1];
  const float* Whh  = (const float*)d_in[2];
  const float* bih  = (const float*)d_in[3];
  const float* bhh  = (const float*)d_in[4];
  const float* Wout = (const float*)d_in[5];
  const float* bout = (const float*)d_in[6];
  float* out = (float*)d_out;
  (void)in_sizes; (void)n_in; (void)out_size;

  // ws layout: [0, 512KB) X as bf16; [512KB, +64MB) h dump.
  const size_t need = (size_t)NB*NT*NP*2 + (size_t)512*65536*2;
  if (d_ws != nullptr && ws_size >= need) {
    __bf16* wsX = (__bf16*)d_ws;
    __bf16* wsH = wsX + (size_t)NB*NT*NP;
    xcvt<<<128, 512, 0, stream>>>(X, wsX);
    // 512 blocks = 32 nets x 16 batch-groups (M=2); 2 blocks/CU pinned by
    // amdgpu_waves_per_eu(4,4) -> 128-reg budget, demand ~125.
    clstm_fused2<<<512, 512, 0, stream>>>(wsX, Wih, Whh, bih, bhh, Wout,
                                          bout, out, wsH);
  } else {
    // R8 fallback: no workspace required.
    clstm_fused_fb<<<256, 512, 0, stream>>>(X, Wih, Whh, bih, bhh, Wout,
                                            bout, out);
  }
}

// Round 7
// 216.705 us; speedup vs baseline: 1.8702x; 1.8702x over previous
//
#include <hip/hip_runtime.h>
#include <stdint.h>

// Problem constants (match reference)
#define NP 32    // num networks (P)
#define NH 128   // hidden (H)
#define NB 32    // batch (B)
#define NT 256   // time (T)
#define FH 512   // 4*H

typedef __attribute__((ext_vector_type(4))) float float4_t;
typedef __attribute__((ext_vector_type(8))) __bf16 bf16x8;
typedef __attribute__((ext_vector_type(4))) __bf16 bf16x4;

static __device__ __forceinline__ float4_t mfma_bf16(bf16x8 a, bf16x8 b, float4_t c) {
  return __builtin_amdgcn_mfma_f32_16x16x32_bf16(a, b, c, 0, 0, 0);
}

#define LOG2E 1.4426950408889634f

// Raw workgroup barrier: drains LDS ops only (cross-wave h visibility), does
// NOT drain vmcnt — pending global loads/stores stay in flight across it.
#define BAR() __asm__ volatile("s_waitcnt lgkmcnt(0)\n\ts_barrier" ::: "memory")

// ---------------------------------------------------------------------------
// R15: ISSUE REDUCTION on the proven R8 base. R14 post-mortem killed the
// overlap theory: 2 co-resident blocks (occ 39.5%) gave EXACTLY zero gain
// (pair = 3480 cyc ~ 2x serial) because R12 already ran at ~93% combined
// issue (MfmaUtil 42 + VALUBusy 51): the step is ISSUE-BOUND on the same-
// wave in-order MFMA+VALU interleave, not exposure-bound. Only cutting
// instruction count helps. R8 budget: 795 cyc MFMA + ~900 cyc VALU +
// ~360 slack per 2060-cyc step. Cuts (target ~450 VALU cyc):
//  1. amdgpu_waves_per_eu(2,2): 512/2 = 256 unified regs (attribute
//     mechanism proven in R14) -> accumulators live in arch VGPRs, no
//     v_accvgpr_read/write traffic (~50-60 instr/step in R8's 108+64 split).
//  2. serial 5-deep gate chains x->h0->h1->h2->h3, bias4 as C-init: kills
//     16 adds + 16 zero-inits + their moves. Latency-safe: 8 indep chains
//     across 2 waves/SIMD at ~19cyc MFMA spacing >> dep latency.
//  3. bf16-X prepass (R14-proven xcvt): 1 dwordx4 load replaces 2 loads +
//     8 cvts + 8 f32 staging regs.
// Head back to fused wave-0 MFMA (R14's ws h-dump cost 67MB HBM for nothing).
// M=4 / 256 blocks is dup-optimal: per-CU MFMA (164/step) can't drop
// without idling CUs. SESSION RULES: launch_bounds 2nd arg never !=1
// (R9-R11 spill death); waves_per_eu is the trusted occupancy knob (R14);
// no DS ops in loop beyond h write/read (R5); co-residency is worthless
// at issue saturation (R14).
// ---------------------------------------------------------------------------

// Prepass: X f32 -> bf16 into ws (same [B][T][P] layout). 262144 elems.
__global__ __launch_bounds__(512, 1) void xcvt(
    const float* __restrict__ X, __bf16* __restrict__ Xb)
{
  const int i = (blockIdx.x * 512 + threadIdx.x) * 4;
  float4_t v = *(const float4_t*)(X + i);
  bf16x4 o;
#pragma unroll
  for (int j = 0; j < 4; ++j) o[j] = (__bf16)v[j];
  *(bf16x4*)(Xb + i) = o;
}

__global__ __attribute__((amdgpu_flat_work_group_size(512, 512),
                          amdgpu_waves_per_eu(2, 2)))
void clstm_fused3(
    const __bf16* __restrict__ Xb, const float* __restrict__ Wih,
    const float* __restrict__ Whh, const float* __restrict__ bih,
    const float* __restrict__ bhh, const float* __restrict__ Wout,
    const float* __restrict__ bout, float* __restrict__ out)
{
  const int net = blockIdx.x >> 3, bq = blockIdx.x & 7;
  const int tid = threadIdx.x;
  const int w = tid >> 6, lane = tid & 63;
  const int quad = lane >> 4, l16 = lane & 15;

  // h A-fragments, double buffered, 4 DISTINCT rows: [buf][kc][kquad][m<4][j]
  __shared__ __bf16 hfrag[2][4][4][4][8];   // 2 KB total

  { ((int*)hfrag)[tid] = 0; }   // h0 = 0, both buffers
  __syncthreads();

  // ---- load weights into register B-fragments (one-time) ----
  // B-frag layout for 16x16x32: lane holds B[k = quad*8 + j][n = l16].
  bf16x8 bfrag[4][5];
  float4_t bias4[4];
#pragma unroll
  for (int g = 0; g < 4; ++g) {
    const float scale = (g == 2) ? (-2.0f*LOG2E) : (-LOG2E);
    const int col = g*NH + w*16 + l16;
#pragma unroll
    for (int kc = 0; kc < 5; ++kc) {
      const float* src = (kc == 0) ? (Wih + ((size_t)net*FH + col)*NP + quad*8)
                                   : (Whh + ((size_t)net*FH + col)*NH + (kc-1)*32 + quad*8);
      bf16x8 bf;
#pragma unroll
      for (int j = 0; j < 8; ++j) bf[j] = (__bf16)(src[j] * scale);
      bfrag[g][kc] = bf;
    }
    const float b = (bih[net*FH + col] + bhh[net*FH + col]) * scale;
    bias4[g] = (float4_t){b, b, b, b};
  }

  // head B-frags: B[k][n] = wout[k] broadcast over all 16 cols n.
  bf16x8 wof[4];
#pragma unroll
  for (int kc = 0; kc < 4; ++kc) {
    const float* wp = Wout + net*NH + kc*32 + quad*8;
#pragma unroll
    for (int j = 0; j < 8; ++j) wof[kc][j] = (__bf16)wp[j];
  }
  const float bo = bout[net];

  // c state, PRE-SCALED by -2log2e (saves a mul on the h critical chain)
  float cs = 0.f;
  const float S2 = -2.0f*LOG2E;

  // x source (bf16 prepass, layout == X): batch bq*4 + (l16&3) (4x dup)
  int xoff = (bq*4 + (l16 & 3))*(NT*NP) + quad*8;

  // h write coords for unit u = w*16 + l16; row = quad (this lane's batch)
  const int kcp = w >> 1, q2 = ((w & 1) << 1) | (l16 >> 3), jj = l16 & 7;

  // head store base: out[(bq*4 + r)*NT*NP + t*NP + net], stored by
  // wave 0, lane 0 (C rows r = batches r, dup across quads).
  float* outp = out + ((size_t)bq*4)*(NT*NP) + net;

  // preload ax for t=0
  bf16x8 ax = *(const bf16x8*)(Xb + xoff);
  xoff += NP;

  for (int t = 0; t < NT; ++t) {
    const int rd = t & 1, wr = rd ^ 1;

    // ---- 1. h A-frags (row = l16&3; 4-lane same-address broadcast) ----
    bf16x8 ah[4];
#pragma unroll
    for (int kc = 0; kc < 4; ++kc)
      ah[kc] = *(const bf16x8*)&hfrag[rd][kc][quad][l16 & 3][0];

    // ---- 2. x-MFMAs first (no LDS dep, fills ds_read latency); acc is
    // the single serial accumulator per gate (bias as C-init) ----
    float4_t acc[4];
#pragma unroll
    for (int g = 0; g < 4; ++g)
      acc[g] = mfma_bf16(ax, bfrag[g][0], bias4[g]);

    // ---- 3. next-x load (ax dead after step 2); guarded; shadow =
    // h-MFMAs + activation + write + BAR ----
    if (t + 1 < NT)
      ax = *(const bf16x8*)(Xb + xoff);
    xoff += NP;

    // ---- 4. h-MFMAs: serial 5-deep chain per gate, 4 indep chains.
    // No a0+a1 adds, no zero-inits, no AGPR round-trips. ----
#pragma unroll
    for (int kc = 0; kc < 4; ++kc)
#pragma unroll
      for (int g = 0; g < 4; ++g)
        acc[g] = mfma_bf16(ah[kc], bfrag[g][kc+1], acc[g]);

    // ---- 5. select this lane's batch (= quad) via cndmask ----
    float gv[4];
#pragma unroll
    for (int g = 0; g < 4; ++g) {
      float a01 = (quad & 1) ? acc[g][1] : acc[g][0];
      float a23 = (quad & 1) ? acc[g][3] : acc[g][2];
      gv[g] = (quad & 2) ? a23 : a01;
    }

    // ---- 6. activation + state update: ONE (batch,unit) pair per lane ----
    float h;
    {
      float ei = __builtin_amdgcn_exp2f(gv[0]);
      float ig = __builtin_amdgcn_rcpf(1.0f + ei);            // sigmoid(i)
      float ef = __builtin_amdgcn_exp2f(gv[1]);
      float fg = __builtin_amdgcn_rcpf(1.0f + ef);            // sigmoid(f)
      float eg = __builtin_amdgcn_exp2f(fminf(gv[2], 126.0f));
      float rg = __builtin_amdgcn_rcpf(1.0f + eg);
      float t0 = S2 * rg;
      float gg2 = t0 - t0 * eg;                               // tanh(g)*S2
      float eo = __builtin_amdgcn_exp2f(gv[3]);
      float og = __builtin_amdgcn_rcpf(1.0f + eo);            // sigmoid(o)
      cs = fg * cs + ig * gg2;                                // c * S2
      float ec = __builtin_amdgcn_exp2f(fminf(cs, 126.0f));
      float rc = __builtin_amdgcn_rcpf(1.0f + ec);
      float th = rc - ec * rc;                                // tanh(c)
      h = og * th;
    }

    // ---- 7. write h' (bf16): 1 ds_write_b16, row = quad ----
    hfrag[wr][kcp][q2][quad][jj] = (__bf16)h;

    // ---- 8. fused head (wave 0; ah = h_{t-1} -> out[t-1]) ----
    if (w == 0 && t > 0) {
      float4_t p0 = {bo, bo, bo, bo};
      float4_t p1 = {0.f, 0.f, 0.f, 0.f};
      p0 = mfma_bf16(ah[0], wof[0], p0);
      p1 = mfma_bf16(ah[2], wof[2], p1);
      p0 = mfma_bf16(ah[1], wof[1], p0);
      p1 = mfma_bf16(ah[3], wof[3], p1);
      float4_t po = p0 + p1;
      if (lane == 0) {   // quad 0: C rows 0..3 = batches 0..3
#pragma unroll
        for (int r = 0; r < 4; ++r)
          outp[(size_t)r*(NT*NP) + (t - 1)*NP] = po[r];
      }
    }

    BAR();  // lgkmcnt-only barrier
  }

  // ---- epilogue: head for t = NT-1 (h_{NT-1} is in hfrag[NT&1]) ----
  if (w == 0) {
    bf16x8 ahf[4];
#pragma unroll
    for (int kc = 0; kc < 4; ++kc)
      ahf[kc] = *(const bf16x8*)&hfrag[NT & 1][kc][quad][l16 & 3][0];
    float4_t p0 = {bo, bo, bo, bo};
    float4_t p1 = {0.f, 0.f, 0.f, 0.f};
    p0 = mfma_bf16(ahf[0], wof[0], p0);
    p1 = mfma_bf16(ahf[2], wof[2], p1);
    p0 = mfma_bf16(ahf[1], wof[1], p0);
    p1 = mfma_bf16(ahf[3], wof[3], p1);
    float4_t po = p0 + p1;
    if (lane == 0) {
#pragma unroll
      for (int r = 0; r < 4; ++r)
        outp[(size_t)r*(NT*NP) + (NT - 1)*NP] = po[r];
    }
  }
}

// ---------------------------------------------------------------------------
// Fallback (ws too small): R8 kernel verbatim — M=4 / 256 blocks, fused
// head, f32 X loads, 219us rocprof. No workspace use.
// ---------------------------------------------------------------------------
__global__ __launch_bounds__(512, 1) void clstm_fused_fb(
    const float* __restrict__ X, const float* __restrict__ Wih,
    const float* __restrict__ Whh, const float* __restrict__ bih,
    const float* __restrict__ bhh, const float* __restrict__ Wout,
    const float* __restrict__ bout, float* __restrict__ out)
{
  const int net = blockIdx.x >> 3, bq = blockIdx.x & 7;
  const int tid = threadIdx.x;
  const int w = tid >> 6, lane = tid & 63;
  const int quad = lane >> 4, l16 = lane & 15;

  __shared__ __bf16 hfrag[2][4][4][4][8];
  { ((int*)hfrag)[tid] = 0; }
  __syncthreads();

  bf16x8 bfrag[4][5];
  float4_t bias4[4];
#pragma unroll
  for (int g = 0; g < 4; ++g) {
    const float scale = (g == 2) ? (-2.0f*LOG2E) : (-LOG2E);
    const int col = g*NH + w*16 + l16;
#pragma unroll
    for (int kc = 0; kc < 5; ++kc) {
      const float* src = (kc == 0) ? (Wih + ((size_t)net*FH + col)*NP + quad*8)
                                   : (Whh + ((size_t)net*FH + col)*NH + (kc-1)*32 + quad*8);
      bf16x8 bf;
#pragma unroll
      for (int j = 0; j < 8; ++j) bf[j] = (__bf16)(src[j] * scale);
      bfrag[g][kc] = bf;
    }
    const float b = (bih[net*FH + col] + bhh[net*FH + col]) * scale;
    bias4[g] = (float4_t){b, b, b, b};
  }

  bf16x8 wof[4];
#pragma unroll
  for (int kc = 0; kc < 4; ++kc) {
    const float* wp = Wout + net*NH + kc*32 + quad*8;
#pragma unroll
    for (int j = 0; j < 8; ++j) wof[kc][j] = (__bf16)wp[j];
  }
  const float bo = bout[net];

  float cs = 0.f;
  const float S2 = -2.0f*LOG2E;

  const float* xrow = X + (size_t)(bq*4 + (l16 & 3))*(NT*NP) + quad*8;
  const int kcp = w >> 1, q2 = ((w & 1) << 1) | (l16 >> 3), jj = l16 & 7;
  float* outp = out + ((size_t)bq*4)*(NT*NP) + net;

  bf16x8 ax;
  {
    float xv0[8];
    *(float4_t*)&xv0[0] = *(const float4_t*)xrow;
    *(float4_t*)&xv0[4] = *(const float4_t*)(xrow + 4);
#pragma unroll
    for (int j = 0; j < 8; ++j) ax[j] = (__bf16)xv0[j];
  }
  const float* xp = xrow + NP;
  float xv[8] = {0.f,0.f,0.f,0.f,0.f,0.f,0.f,0.f};

  for (int t = 0; t < NT; ++t) {
    const int rd = t & 1, wr = rd ^ 1;
    bf16x8 ah[4];
#pragma unroll
    for (int kc = 0; kc < 4; ++kc)
      ah[kc] = *(const bf16x8*)&hfrag[rd][kc][quad][l16 & 3][0];
    float4_t accx[4];
#pragma unroll
    for (int g = 0; g < 4; ++g)
      accx[g] = mfma_bf16(ax, bfrag[g][0], bias4[g]);
    if (t + 1 < NT) {
      *(float4_t*)&xv[0] = *(const float4_t*)xp;
      *(float4_t*)&xv[4] = *(const float4_t*)(xp + 4);
    }
    float4_t acc[4];
#pragma unroll
    for (int g = 0; g < 4; ++g) {
      float4_t a0 = mfma_bf16(ah[0], bfrag[g][1], accx[g]);
      float4_t a1 = mfma_bf16(ah[2], bfrag[g][3], (float4_t){0.f,0.f,0.f,0.f});
      a0 = mfma_bf16(ah[1], bfrag[g][2], a0);
      a1 = mfma_bf16(ah[3], bfrag[g][4], a1);
      acc[g] = a0 + a1;
    }
    float gv[4];
#pragma unroll
    for (int g = 0; g < 4; ++g) {
      float a01 = (quad & 1) ? acc[g][1] : acc[g][0];
      float a23 = (quad & 1) ? acc[g][3] : acc[g][2];
      gv[g] = (quad & 2) ? a23 : a01;
    }
    float h;
    {
      float ei = __builtin_amdgcn_exp2f(gv[0]);
      float ig = __builtin_amdgcn_rcpf(1.0f + ei);
      float ef = __builtin_amdgcn_exp2f(gv[1]);
      float fg = __builtin_amdgcn_rcpf(1.0f + ef);
      float eg = __builtin_amdgcn_exp2f(fminf(gv[2], 126.0f));
      float rg = __builtin_amdgcn_rcpf(1.0f + eg);
      float t0 = S2 * rg;
      float gg2 = t0 - t0 * eg;
      float eo = __builtin_amdgcn_exp2f(gv[3]);
      float og = __builtin_amdgcn_rcpf(1.0f + eo);
      cs = fg * cs + ig * gg2;
      float ec = __builtin_amdgcn_exp2f(fminf(cs, 126.0f));
      float rc = __builtin_amdgcn_rcpf(1.0f + ec);
      float th = rc - ec * rc;
      h = og * th;
    }
    hfrag[wr][kcp][q2][quad][jj] = (__bf16)h;
    if (w == 0 && t > 0) {
      float4_t p0 = {bo, bo, bo, bo};
      float4_t p1 = {0.f, 0.f, 0.f, 0.f};
      p0 = mfma_bf16(ah[0], wof[0], p0);
      p1 = mfma_bf16(ah[2], wof[2], p1);
      p0 = mfma_bf16(ah[1], wof[1], p0);
      p1 = mfma_bf16(ah[3], wof[3], p1);
      float4_t po = p0 + p1;
      if (lane == 0) {
#pragma unroll
        for (int r = 0; r < 4; ++r)
          outp[(size_t)r*(NT*NP) + (t - 1)*NP] = po[r];
      }
    }
#pragma unroll
    for (int j = 0; j < 8; ++j) ax[j] = (__bf16)xv[j];
    xp += NP;
    BAR();
  }

  if (w == 0) {
    bf16x8 ahf[4];
#pragma unroll
    for (int kc = 0; kc < 4; ++kc)
      ahf[kc] = *(const bf16x8*)&hfrag[NT & 1][kc][quad][l16 & 3][0];
    float4_t p0 = {bo, bo, bo, bo};
    float4_t p1 = {0.f, 0.f, 0.f, 0.f};
    p0 = mfma_bf16(ahf[0], wof[0], p0);
    p1 = mfma_bf16(ahf[2], wof[2], p1);
    p0 = mfma_bf16(ahf[1], wof[1], p0);
    p1 = mfma_bf16(ahf[3], wof[3], p1);
    float4_t po = p0 + p1;
    if (lane == 0) {
#pragma unroll
      for (int r = 0; r < 4; ++r)
        outp[(size_t)r*(NT*NP) + (NT - 1)*NP] = po[r];
    }
  }
}

extern "C" void kernel_launch(void* const* d_in, const int* in_sizes, int n_in,
                              void* d_out, int out_size, void* d_ws, size_t ws_size,
                              hipStream_t stream) {
  const float* X    = (const float*)d_in[0];
  const float* Wih  = (const float*)d_in[1];
  const float* Whh  = (const float*)d_in[2];
  const float* bih  = (const float*)d_in[3];
  const float* bhh  = (const float*)d_in[4];
  const float* Wout = (const float*)d_in[5];
  const float* bout = (const float*)d_in[6];
  float* out = (float*)d_out;
  (void)in_sizes; (void)n_in; (void)out_size;

  // ws layout: [0, 512KB) X as bf16.
  const size_t need = (size_t)NB*NT*NP*2;
  if (d_ws != nullptr && ws_size >= need) {
    __bf16* wsX = (__bf16*)d_ws;
    xcvt<<<128, 512, 0, stream>>>(X, wsX);
    // 256 blocks = 32 nets x 8 batch-groups (M=4); 1 block/CU; 256-reg
    // budget via waves_per_eu(2,2).
    clstm_fused3<<<256, 512, 0, stream>>>(wsX, Wih, Whh, bih, bhh, Wout,
                                          bout, out);
  } else {
    // R8 fallback: no workspace required.
    clstm_fused_fb<<<256, 512, 0, stream>>>(X, Wih, Whh, bih, bhh, Wout,
                                            bout, out);
  }
}